// Round 7
// baseline (7068.672 us; speedup 1.0000x reference)
//
#include <hip/hip_runtime.h>

// GhostGRU persistent-RNN kernel for MI355X (gfx950), round 9.
// Base: round-8 (3660us dispatch, best passing). Theme: decouple flag posts
// from all-wave barriers so consumers' poll overlaps the producer's drain.
//  D1. rflag posted by wave 0 itself (own DRAIN + store) BEFORE the B-end
//      syncthreads (barrier kept: it fences wave-1's u writes in LDS).
//  D2. post(3t+2) syncthreads removed; wave 2 DRAINs its newh stores and
//      posts nflag itself; deferred out stores after the post.
//  D3. post(3t+3) syncthreads removed; wave 3 likewise for gflag.
//  D4. x_{t+1} prefetch issued at C-top (not post-S1) so wave-0's DRAIN in B
//      waits only its 2 rstate store acks, not 4 HBM loads.
//  D5. wait_flags: 2-deep pipelined poll (issue next load before consuming
//      previous -> counted vmcnt(1) wait, halved poll period); s_sleep gone.
// Flag-slot ordering across posters (w0:3t+1, w2:3t+2, w3:3t+3, w0:3t+4...)
// is preserved: each poster's store is force-drained by a subsequent all-wave
// syncthreads (S1b -> S2 -> [w2 post] -> S3 -> [w3 post] -> S1 -> [w0 post])
// that precedes the next poster's issue. LDS overwrites re-audited: every
// region write is separated from its readers by S1/S2/S3 or a cross-WG wait
// that transitively contains them.

typedef unsigned short ushort_t;
typedef unsigned long long ull_t;
typedef __attribute__((ext_vector_type(8))) short short8;   // 8 x bf16 (4 VGPRs)
typedef __attribute__((ext_vector_type(4))) float f32x4;

#define NB 128
#define NT 512
#define NF 256
#define NH 1024
#define KGATE 1280

#define AT_LOAD(p)     __hip_atomic_load((p), __ATOMIC_RELAXED, __HIP_MEMORY_SCOPE_AGENT)
#define AT_STORE(p,v)  __hip_atomic_store((p), (v), __ATOMIC_RELAXED, __HIP_MEMORY_SCOPE_AGENT)

// Per-wave full drain (vmcnt/lgkmcnt/expcnt = 0) + scheduling fences so the
// compiler cannot move the subsequent flag store above the wait. Proven
// primitive (compiled + passed in round 7).
#define DRAIN() do { __builtin_amdgcn_sched_barrier(0); \
                     __builtin_amdgcn_s_waitcnt(0);     \
                     __builtin_amdgcn_sched_barrier(0); } while (0)

__device__ __forceinline__ float bf2f(ushort_t u) {
  union { unsigned int i; float f; } v; v.i = ((unsigned int)u) << 16; return v.f;
}
__device__ __forceinline__ ushort_t f2bf(float f) {
  union { float f; unsigned int i; } v; v.f = f;
  unsigned int r = v.i + 0x7FFFu + ((v.i >> 16) & 1u);
  return (ushort_t)(r >> 16);
}
__device__ __forceinline__ float sigmoidf_(float x) { return 1.f / (1.f + __expf(-x)); }
__device__ __forceinline__ float tanhf_(float x) {
  float e = __expf(2.f * x); return 1.f - 2.f / (e + 1.f);
}

// Wave-parallel wait, 2-deep pipelined: lane i polls flags[i&31]; the next
// poll load is issued before the previous value is consumed, so the compiler
// waits with vmcnt(1) and the poll period halves. Flags are monotonic, so
// exiting on the older value is safe.
__device__ __forceinline__ void wait_flags(const unsigned* flags, unsigned tgt) {
  const int sl = (int)(threadIdx.x & 31u);
  unsigned f = AT_LOAD(&flags[sl]);
  for (;;) {
    unsigned fn = AT_LOAD(&flags[sl]);
    if (__all((int)(f >= tgt))) break;
    f = fn;
  }
  __builtin_amdgcn_sched_barrier(0);   // keep staged loads below the wait
}

__device__ __forceinline__ short8 pack_bf16_8(const float* p) {
  float4 a = *(const float4*)p;
  float4 b = *(const float4*)(p + 4);
  short8 f;
  f[0] = (short)f2bf(a.x); f[1] = (short)f2bf(a.y);
  f[2] = (short)f2bf(a.z); f[3] = (short)f2bf(a.w);
  f[4] = (short)f2bf(b.x); f[5] = (short)f2bf(b.y);
  f[6] = (short)f2bf(b.z); f[7] = (short)f2bf(b.w);
  return f;
}

// counters layout (uints): group g's 32 flag slots at [g*64 .. g*64+32).
__global__ void __launch_bounds__(256, 1) ghost_gru_persistent(
    const float* __restrict__ x, const float* __restrict__ hidden,
    const float* __restrict__ Wg, const float* __restrict__ Wc,
    const float* __restrict__ Wgh, const float* __restrict__ bg,
    const float* __restrict__ bc, const float* __restrict__ bgh,
    float* __restrict__ out, unsigned int* __restrict__ hbuf_u,
    unsigned int* __restrict__ rs_u, unsigned int* __restrict__ counters)
{
  const int wgid = blockIdx.x;
  const int g    = wgid & 7;      // group (XCD-affine heuristic; perf only)
  const int memb = wgid >> 3;     // member 0..31 within group
  const int b0   = g * 16;        // batch base
  const int tid  = threadIdx.x;
  const int wv   = tid >> 6;      // wave 0..3
  const int lane = tid & 63;
  const int lq   = lane >> 4;     // quad 0..3
  const int ln   = lane & 15;
  unsigned* flags = counters + g * 64;

  // A-staging (bf16): [16 batches][ x(0..255) | ghost(256..767) | newh(768..1279)
  //   | rstate(1280..1791) | u-f32(1792..1823) | pad ]
  __shared__ __align__(16) ushort_t Abuf[16][1832];

  #define LDA(kc)  (*(const short8*)&Abuf[ln][(kc) * 32 + lq * 8])
  #define LDR(kc)  (*(const short8*)&Abuf[ln][1280 + ((kc) - 24) * 32 + lq * 8])
  #define MFMA(a, b, c) __builtin_amdgcn_mfma_f32_16x16x32_bf16((a), (b), (c), 0, 0, 0)

  // VGPR-resident weight fragments. u-localization mapping: wave 0 -> r-cols
  // [16m,+16); wave 1 -> u-cols [512+16m,+16); wave 2 -> cand [16m,+16);
  // wave 3 -> ghost [16m,+16) (K=512).
  short8 wfrag[40];
  int ncol0;
  float biasv;
  if (wv == 0) {
    ncol0 = memb * 16;
    const float* wp = Wg + (size_t)(ncol0 + ln) * KGATE + lq * 8;
    #pragma unroll
    for (int kc = 0; kc < 40; ++kc) wfrag[kc] = pack_bf16_8(wp + kc * 32);
    biasv = bg[ncol0 + ln];
  } else if (wv == 1) {
    ncol0 = 512 + memb * 16;
    const float* wp = Wg + (size_t)(ncol0 + ln) * KGATE + lq * 8;
    #pragma unroll
    for (int kc = 0; kc < 40; ++kc) wfrag[kc] = pack_bf16_8(wp + kc * 32);
    biasv = bg[ncol0 + ln];
  } else if (wv == 2) {
    ncol0 = memb * 16;
    const float* wp = Wc + (size_t)(ncol0 + ln) * KGATE + lq * 8;
    #pragma unroll
    for (int kc = 0; kc < 40; ++kc) wfrag[kc] = pack_bf16_8(wp + kc * 32);
    biasv = bc[ncol0 + ln];
  } else {
    ncol0 = memb * 16;
    const float* wp = Wgh + (size_t)(ncol0 + ln) * 512 + lq * 8;
    #pragma unroll
    for (int kc = 0; kc < 16; ++kc) wfrag[kc] = pack_bf16_8(wp + kc * 32);
    biasv = bgh[ncol0 + ln];
  }

  // fp32 master copy of new_h state, held by cand wave across all steps.
  float hreg[4];
  if (wv == 2) {
    #pragma unroll
    for (int r = 0; r < 4; ++r)
      hreg[r] = hidden[(size_t)(b0 + lq * 4 + r) * NH + 512 + ncol0 + ln];
  }

  const ull_t* hbuf64 = (const ull_t*)hbuf_u;
  const ull_t* rs64   = (const ull_t*)rs_u;

  // ---- prologue: stage newh(h0) + x_0 into LDS ----
  {
    ull_t nv[8];
    #pragma unroll
    for (int k = 0; k < 8; ++k) {
      int j = tid + k * 256;               // 0..2047 over 16 rows x 128 ull
      nv[k] = AT_LOAD(&hbuf64[(size_t)(b0 + (j >> 7)) * 256 + 128 + (j & 127)]);
    }
    #pragma unroll
    for (int k = 0; k < 8; ++k) {
      int j = tid + k * 256;
      *(ull_t*)&Abuf[j >> 7][768 + 4 * (j & 127)] = nv[k];
    }
    #pragma unroll
    for (int k = 0; k < 4; ++k) {
      int i = tid + k * 256;
      int row = i >> 6, c4 = (i & 63) * 4;
      float4 v = *(const float4*)&x[((size_t)(b0 + row) * NT + 0) * NF + c4];
      *(ushort4*)&Abuf[row][c4] =
          make_ushort4(f2bf(v.x), f2bf(v.y), f2bf(v.z), f2bf(v.w));
    }
  }
  __syncthreads();

  float4 xv[4];   // x_{t+1} prefetch registers

  #pragma unroll 1
  for (int t = 0; t < NT; ++t) {
    const int cur = t & 1, nxt = cur ^ 1;
    const ull_t* hsrc64 = hbuf64 + (size_t)cur * NB * 256;
    unsigned*    hdst   = hbuf_u + (size_t)nxt * NB * 512;
    const ull_t* hdst64 = (const ull_t*)hdst;

    f32x4 ga0 = {0.f, 0.f, 0.f, 0.f}, ga1 = {0.f, 0.f, 0.f, 0.f};  // gate (wv<2)
    f32x4 ca0 = {0.f, 0.f, 0.f, 0.f}, ca1 = {0.f, 0.f, 0.f, 0.f};  // cand (wv2)

    // ---- A: loop top. Waves 2/3: wait ghost(t-1) + stage it. Waves 0/1:
    //      ghost-independent gate frags (x: 0..7, newh: 24..39). ----
    if (wv >= 2) {
      wait_flags(flags, 3u * (unsigned)t);   // ghost of step t-1 posted
      const int l = tid & 127;               // 0..127 within waves 2/3
      ull_t gv[16];
      #pragma unroll
      for (int k = 0; k < 16; ++k) {
        int j = l + k * 128;
        gv[k] = AT_LOAD(&hsrc64[(size_t)(b0 + (j >> 7)) * 256 + (j & 127)]);
      }
      #pragma unroll
      for (int k = 0; k < 16; ++k) {
        int j = l + k * 128;
        *(ull_t*)&Abuf[j >> 7][256 + 4 * (j & 127)] = gv[k];
      }
    } else {
      #pragma unroll
      for (int kc = 0; kc < 8; kc += 2) {
        ga0 = MFMA(LDA(kc), wfrag[kc], ga0);
        ga1 = MFMA(LDA(kc + 1), wfrag[kc + 1], ga1);
      }
      #pragma unroll
      for (int kc = 24; kc < 40; kc += 2) {
        ga0 = MFMA(LDA(kc), wfrag[kc], ga0);
        ga1 = MFMA(LDA(kc + 1), wfrag[kc + 1], ga1);
      }
    }
    __syncthreads();   // S1: ghost staged; safe to read [256..768)

    // ---- B: phase-1 completion (wv0/1: ghost frags 8..23 + activation);
    //      wave 2: its 24 x+ghost cand frags. Wave 0 posts rflag itself
    //      after draining only its own rstate stores (D1). ----
    if (wv < 2) {
      #pragma unroll
      for (int kc = 8; kc < 24; kc += 2) {
        ga0 = MFMA(LDA(kc), wfrag[kc], ga0);
        ga1 = MFMA(LDA(kc + 1), wfrag[kc + 1], ga1);
      }
      const int n = ncol0 + ln;
      if (wv == 0) {      // r-gate -> rstate = r * h_old[newh part] (cross-WG)
        #pragma unroll
        for (int r = 0; r < 4; ++r) {
          int row = lq * 4 + r;
          float s = sigmoidf_(ga0[r] + ga1[r] + biasv);
          float hold = bf2f(Abuf[row][768 + n]);
          unsigned hv = (unsigned)f2bf(s * hold);
          unsigned pv = (unsigned)__shfl_xor((int)hv, 1);
          if (!(ln & 1))
            AT_STORE(&rs_u[(size_t)(b0 + row) * 256 + (n >> 1)], hv | (pv << 16));
        }
        DRAIN();          // wave-0-local: only rstate store acks pending (D4)
        if (tid == 0) AT_STORE(&flags[memb], 3u * (unsigned)t + 1u);
      } else {            // u-gate -> LDS only (consumed by this WG's cand wave)
        #pragma unroll
        for (int r = 0; r < 4; ++r) {
          int row = lq * 4 + r;
          float s = sigmoidf_(ga0[r] + ga1[r] + biasv);
          ((float*)&Abuf[row][1792])[ln] = s;
        }
      }
    } else if (wv == 2) {
      #pragma unroll
      for (int kc = 0; kc < 24; kc += 2) {
        ca0 = MFMA(LDA(kc), wfrag[kc], ca0);
        ca1 = MFMA(LDA(kc + 1), wfrag[kc + 1], ca1);
      }
    }
    __syncthreads();   // S1b: u-fence; also force-drains wave-0's flag store

    // ---- C: x prefetch issue (D4), u read, rstate exchange ----
    {
      const int tn = (t + 1 < NT) ? t + 1 : t;
      #pragma unroll
      for (int k = 0; k < 4; ++k) {
        int i = tid + k * 256;
        xv[k] = *(const float4*)&x[((size_t)(b0 + (i >> 6)) * NT + tn) * NF + (i & 63) * 4];
      }
    }
    float uval[4];
    if (wv == 2) {        // u from LDS (written by wave 1 before S1b)
      #pragma unroll
      for (int r = 0; r < 4; ++r)
        uval[r] = ((const float*)&Abuf[lq * 4 + r][1792])[ln];
    }
    wait_flags(flags, 3u * (unsigned)t + 1u);
    {
      ull_t rv[8];
      #pragma unroll
      for (int k = 0; k < 8; ++k) {
        int j = tid + k * 256;
        rv[k] = AT_LOAD(&rs64[(size_t)(b0 + (j >> 7)) * 128 + (j & 127)]);
      }
      #pragma unroll
      for (int k = 0; k < 8; ++k) {
        int j = tid + k * 256;
        *(ull_t*)&Abuf[j >> 7][1280 + 4 * (j & 127)] = rv[k];
      }
    }
    __syncthreads();   // S2: rstate staged

    // ---- D: phase-2 late (wv2): rstate frags, hnew, state stores, own
    //      drain + nflag post (D2), then deferred out stores. ----
    if (wv == 2) {
      #pragma unroll
      for (int kc = 24; kc < 40; kc += 2) {
        ca0 = MFMA(LDR(kc), wfrag[kc], ca0);
        ca1 = MFMA(LDR(kc + 1), wfrag[kc + 1], ca1);
      }
      const int n = ncol0 + ln;
      float hn[4];
      #pragma unroll
      for (int r = 0; r < 4; ++r) {
        int row = lq * 4 + r;
        float cv = tanhf_(ca0[r] + ca1[r] + biasv);
        float u = uval[r];
        float hnew = u * hreg[r] + (1.f - u) * cv;
        hreg[r] = hnew; hn[r] = hnew;
        unsigned hv = (unsigned)f2bf(hnew);
        unsigned pv = (unsigned)__shfl_xor((int)hv, 1);
        if (!(ln & 1))
          AT_STORE(&hdst[(size_t)(b0 + row) * 512 + 256 + (n >> 1)], hv | (pv << 16));
      }
      DRAIN();            // wave-2-local: newh store acks (x loads long done)
      if (tid == 128) AT_STORE(&flags[memb], 3u * (unsigned)t + 2u);
      #pragma unroll
      for (int r = 0; r < 4; ++r) {   // deferred out: acks drain at S3
        int b = b0 + lq * 4 + r;
        out[((size_t)b * NT + t) * NH + 512 + n] = hn[r];
        if (t == NT - 1) out[(size_t)NB * NT * NH + (size_t)b * NH + 512 + n] = hn[r];
      }
    }
    wait_flags(flags, 3u * (unsigned)t + 2u);

    // ---- E: stage fresh newh (8 ull each) + x_{t+1} conversion ----
    {
      ull_t nv[8];
      #pragma unroll
      for (int k = 0; k < 8; ++k) {
        int j = tid + k * 256;
        nv[k] = AT_LOAD(&hdst64[(size_t)(b0 + (j >> 7)) * 256 + 128 + (j & 127)]);
      }
      #pragma unroll
      for (int k = 0; k < 8; ++k) {
        int j = tid + k * 256;
        *(ull_t*)&Abuf[j >> 7][768 + 4 * (j & 127)] = nv[k];
      }
      #pragma unroll
      for (int k = 0; k < 4; ++k) {
        int i = tid + k * 256;
        int row = i >> 6, c4 = (i & 63) * 4;
        *(ushort4*)&Abuf[row][c4] =
            make_ushort4(f2bf(xv[k].x), f2bf(xv[k].y), f2bf(xv[k].z), f2bf(xv[k].w));
      }
    }
    __syncthreads();   // S3: newh_t + x_{t+1} staged; drains wave-2 flag+outs

    // ---- F: phase 3 (wv3): ghost GEMM, state stores, own drain + gflag
    //      post (D3), deferred outs. Others fall through to loop top. ----
    if (wv == 3) {
      f32x4 acc = {0.f, 0.f, 0.f, 0.f};
      #pragma unroll
      for (int kc = 0; kc < 16; ++kc)
        acc = MFMA((*(const short8*)&Abuf[ln][768 + kc * 32 + lq * 8]), wfrag[kc], acc);
      const int n = ncol0 + ln;
      float gvv[4];
      #pragma unroll
      for (int r = 0; r < 4; ++r) {
        int row = lq * 4 + r;
        float gv = tanhf_(acc[r] + biasv);
        gvv[r] = gv;
        unsigned hv = (unsigned)f2bf(gv);
        unsigned pv = (unsigned)__shfl_xor((int)hv, 1);
        if (!(ln & 1))
          AT_STORE(&hdst[(size_t)(b0 + row) * 512 + (n >> 1)], hv | (pv << 16));
      }
      DRAIN();            // wave-3-local: ghost state store acks
      if (tid == 192) AT_STORE(&flags[memb], 3u * (unsigned)t + 3u);
      #pragma unroll
      for (int r = 0; r < 4; ++r) {   // deferred out: acks drain at next S1
        int b = b0 + lq * 4 + r;
        out[((size_t)b * NT + t) * NH + n] = gvv[r];
        if (t == NT - 1) out[(size_t)NB * NT * NH + (size_t)b * NH + n] = gvv[r];
      }
    }
    // no trailing barrier: loop-top wait (wv2/3) gates on gflag; wv0/1 are
    // gated transitively by S1.
  }
  #undef LDA
  #undef LDR
  #undef MFMA
}

__global__ void init_kernel(const float* __restrict__ hidden,
                            unsigned int* __restrict__ hbuf_u,
                            unsigned int* __restrict__ counters) {
  int i = blockIdx.x * blockDim.x + threadIdx.x;
  if (i < NB * 512) {  // pack h0 into bf16 pairs; hbuf[0] = h0
    unsigned lo = (unsigned)f2bf(hidden[2 * i]);
    unsigned hi = (unsigned)f2bf(hidden[2 * i + 1]);
    hbuf_u[i] = lo | (hi << 16);
  }
  if (i < 512) counters[i] = 0;  // 8 groups x 64-uint flag blocks
}

extern "C" void kernel_launch(void* const* d_in, const int* in_sizes, int n_in,
                              void* d_out, int out_size, void* d_ws, size_t ws_size,
                              hipStream_t stream) {
  (void)in_sizes; (void)n_in; (void)out_size; (void)ws_size;
  const float* x      = (const float*)d_in[0];
  const float* hidden = (const float*)d_in[1];
  const float* Wg     = (const float*)d_in[2];
  const float* Wc     = (const float*)d_in[3];
  const float* Wgh    = (const float*)d_in[4];
  const float* bg     = (const float*)d_in[5];
  const float* bc     = (const float*)d_in[6];
  const float* bgh    = (const float*)d_in[7];
  float* out = (float*)d_out;

  char* ws = (char*)d_ws;
  unsigned int* hbuf_u   = (unsigned int*)(ws);         // 2 * 128*512 uints = 512 KB
  unsigned int* rs_u     = (unsigned int*)(ws + 524288);// 128*256 uints = 128 KB
  unsigned int* counters = (unsigned int*)(ws + 655360);// 512 uints = 2 KB

  init_kernel<<<dim3(256), dim3(256), 0, stream>>>(hidden, hbuf_u, counters);
  ghost_gru_persistent<<<dim3(256), dim3(256), 0, stream>>>(
      x, hidden, Wg, Wc, Wgh, bg, bc, bgh, out, hbuf_u, rs_u, counters);
}

// Round 8
// 3826.296 us; speedup vs baseline: 1.8474x; 1.8474x over previous
//
#include <hip/hip_runtime.h>

// GhostGRU persistent-RNN kernel for MI355X (gfx950), round 10.
// Rounds 7/9 (per-wave DRAIN posts) both regressed badly -> the round-8
// skeleton (barrier-coupled post_flag, s_sleep poll, post-S1 x-prefetch) is
// the proven protocol and is kept EXACTLY. Round 10 = round 8 + two local,
// protocol-preserving tweaks:
//  1. Waves 2/3 skip the C- and E-polls (S2/S3 gate their reads anyway);
//     waves 0/1 poll + stage 16x8B each. Halves poll traffic per exchange
//     and lets the critical cand wave reach its barriers early.
//  2. x_{t+1} bf16 conversion hoisted above the E-wait (LDS-only; the x
//     region's readers all complete before the 3t+1 barrier).

typedef unsigned short ushort_t;
typedef unsigned long long ull_t;
typedef __attribute__((ext_vector_type(8))) short short8;   // 8 x bf16 (4 VGPRs)
typedef __attribute__((ext_vector_type(4))) float f32x4;

#define NB 128
#define NT 512
#define NF 256
#define NH 1024
#define KGATE 1280

#define AT_LOAD(p)     __hip_atomic_load((p), __ATOMIC_RELAXED, __HIP_MEMORY_SCOPE_AGENT)
#define AT_STORE(p,v)  __hip_atomic_store((p), (v), __ATOMIC_RELAXED, __HIP_MEMORY_SCOPE_AGENT)

__device__ __forceinline__ float bf2f(ushort_t u) {
  union { unsigned int i; float f; } v; v.i = ((unsigned int)u) << 16; return v.f;
}
__device__ __forceinline__ ushort_t f2bf(float f) {
  union { float f; unsigned int i; } v; v.f = f;
  unsigned int r = v.i + 0x7FFFu + ((v.i >> 16) & 1u);
  return (ushort_t)(r >> 16);
}
__device__ __forceinline__ float sigmoidf_(float x) { return 1.f / (1.f + __expf(-x)); }
__device__ __forceinline__ float tanhf_(float x) {
  float e = __expf(2.f * x); return 1.f - 2.f / (e + 1.f);
}

// Post this WG's arrival at cumulative phase value `val`. __syncthreads drains
// vmcnt(0) for every wave => all this WG's data stores are at the LLC before
// the single-writer flag slot is updated. (Proven round-6/8 primitive.)
__device__ __forceinline__ void post_flag(unsigned* flags, int memb, unsigned val) {
  __syncthreads();
  if (threadIdx.x == 0) AT_STORE(&flags[memb], val);
}

// Wave-parallel wait: lane i polls flags[i&31]; one coalesced load covers all
// 32 slots. Flags are monotonic, so exit is stable.
__device__ __forceinline__ void wait_flags(const unsigned* flags, unsigned tgt) {
  const int sl = (int)(threadIdx.x & 31u);
  for (;;) {
    unsigned f = AT_LOAD(&flags[sl]);
    if (__all((int)(f >= tgt))) break;
    __builtin_amdgcn_s_sleep(1);
  }
  __builtin_amdgcn_sched_barrier(0);   // keep staged loads below the wait
}

__device__ __forceinline__ short8 pack_bf16_8(const float* p) {
  float4 a = *(const float4*)p;
  float4 b = *(const float4*)(p + 4);
  short8 f;
  f[0] = (short)f2bf(a.x); f[1] = (short)f2bf(a.y);
  f[2] = (short)f2bf(a.z); f[3] = (short)f2bf(a.w);
  f[4] = (short)f2bf(b.x); f[5] = (short)f2bf(b.y);
  f[6] = (short)f2bf(b.z); f[7] = (short)f2bf(b.w);
  return f;
}

// counters layout (uints): group g's 32 flag slots at [g*64 .. g*64+32).
__global__ void __launch_bounds__(256, 1) ghost_gru_persistent(
    const float* __restrict__ x, const float* __restrict__ hidden,
    const float* __restrict__ Wg, const float* __restrict__ Wc,
    const float* __restrict__ Wgh, const float* __restrict__ bg,
    const float* __restrict__ bc, const float* __restrict__ bgh,
    float* __restrict__ out, unsigned int* __restrict__ hbuf_u,
    unsigned int* __restrict__ rs_u, unsigned int* __restrict__ counters)
{
  const int wgid = blockIdx.x;
  const int g    = wgid & 7;      // group (XCD-affine heuristic; perf only)
  const int memb = wgid >> 3;     // member 0..31 within group
  const int b0   = g * 16;        // batch base
  const int tid  = threadIdx.x;
  const int wv   = tid >> 6;      // wave 0..3
  const int lane = tid & 63;
  const int lq   = lane >> 4;     // quad 0..3
  const int ln   = lane & 15;
  unsigned* flags = counters + g * 64;

  // A-staging (bf16): [16 batches][ x(0..255) | ghost(256..767) | newh(768..1279)
  //   | rstate(1280..1791) | u-f32(1792..1823) | pad ]
  __shared__ __align__(16) ushort_t Abuf[16][1832];

  #define LDA(kc)  (*(const short8*)&Abuf[ln][(kc) * 32 + lq * 8])
  #define LDR(kc)  (*(const short8*)&Abuf[ln][1280 + ((kc) - 24) * 32 + lq * 8])
  #define MFMA(a, b, c) __builtin_amdgcn_mfma_f32_16x16x32_bf16((a), (b), (c), 0, 0, 0)

  // VGPR-resident weight fragments. u-localization mapping: wave 0 -> r-cols
  // [16m,+16); wave 1 -> u-cols [512+16m,+16); wave 2 -> cand [16m,+16);
  // wave 3 -> ghost [16m,+16) (K=512).
  short8 wfrag[40];
  int ncol0;
  float biasv;
  if (wv == 0) {
    ncol0 = memb * 16;
    const float* wp = Wg + (size_t)(ncol0 + ln) * KGATE + lq * 8;
    #pragma unroll
    for (int kc = 0; kc < 40; ++kc) wfrag[kc] = pack_bf16_8(wp + kc * 32);
    biasv = bg[ncol0 + ln];
  } else if (wv == 1) {
    ncol0 = 512 + memb * 16;
    const float* wp = Wg + (size_t)(ncol0 + ln) * KGATE + lq * 8;
    #pragma unroll
    for (int kc = 0; kc < 40; ++kc) wfrag[kc] = pack_bf16_8(wp + kc * 32);
    biasv = bg[ncol0 + ln];
  } else if (wv == 2) {
    ncol0 = memb * 16;
    const float* wp = Wc + (size_t)(ncol0 + ln) * KGATE + lq * 8;
    #pragma unroll
    for (int kc = 0; kc < 40; ++kc) wfrag[kc] = pack_bf16_8(wp + kc * 32);
    biasv = bc[ncol0 + ln];
  } else {
    ncol0 = memb * 16;
    const float* wp = Wgh + (size_t)(ncol0 + ln) * 512 + lq * 8;
    #pragma unroll
    for (int kc = 0; kc < 16; ++kc) wfrag[kc] = pack_bf16_8(wp + kc * 32);
    biasv = bgh[ncol0 + ln];
  }

  // fp32 master copy of new_h state, held by cand wave across all steps.
  float hreg[4];
  if (wv == 2) {
    #pragma unroll
    for (int r = 0; r < 4; ++r)
      hreg[r] = hidden[(size_t)(b0 + lq * 4 + r) * NH + 512 + ncol0 + ln];
  }

  const ull_t* hbuf64 = (const ull_t*)hbuf_u;
  const ull_t* rs64   = (const ull_t*)rs_u;

  // ---- prologue: stage newh(h0) + x_0 into LDS ----
  {
    ull_t nv[8];
    #pragma unroll
    for (int k = 0; k < 8; ++k) {
      int j = tid + k * 256;               // 0..2047 over 16 rows x 128 ull
      nv[k] = AT_LOAD(&hbuf64[(size_t)(b0 + (j >> 7)) * 256 + 128 + (j & 127)]);
    }
    #pragma unroll
    for (int k = 0; k < 8; ++k) {
      int j = tid + k * 256;
      *(ull_t*)&Abuf[j >> 7][768 + 4 * (j & 127)] = nv[k];
    }
    #pragma unroll
    for (int k = 0; k < 4; ++k) {
      int i = tid + k * 256;
      int row = i >> 6, c4 = (i & 63) * 4;
      float4 v = *(const float4*)&x[((size_t)(b0 + row) * NT + 0) * NF + c4];
      *(ushort4*)&Abuf[row][c4] =
          make_ushort4(f2bf(v.x), f2bf(v.y), f2bf(v.z), f2bf(v.w));
    }
  }
  __syncthreads();

  float4 xv[4];   // x_{t+1} prefetch registers

  #pragma unroll 1
  for (int t = 0; t < NT; ++t) {
    const int cur = t & 1, nxt = cur ^ 1;
    const ull_t* hsrc64 = hbuf64 + (size_t)cur * NB * 256;
    unsigned*    hdst   = hbuf_u + (size_t)nxt * NB * 512;
    const ull_t* hdst64 = (const ull_t*)hdst;

    f32x4 ga0 = {0.f, 0.f, 0.f, 0.f}, ga1 = {0.f, 0.f, 0.f, 0.f};  // gate (wv<2)
    f32x4 ca0 = {0.f, 0.f, 0.f, 0.f}, ca1 = {0.f, 0.f, 0.f, 0.f};  // cand (wv2)

    // ---- A: loop top. Waves 2/3: wait ghost(t-1) + stage it. Waves 0/1:
    //      ghost-independent gate frags (x: 0..7, newh: 24..39). ----
    if (wv >= 2) {
      wait_flags(flags, 3u * (unsigned)t);   // ghost of step t-1 posted
      const int l = tid & 127;               // 0..127 within waves 2/3
      ull_t gv[16];
      #pragma unroll
      for (int k = 0; k < 16; ++k) {
        int j = l + k * 128;
        gv[k] = AT_LOAD(&hsrc64[(size_t)(b0 + (j >> 7)) * 256 + (j & 127)]);
      }
      #pragma unroll
      for (int k = 0; k < 16; ++k) {
        int j = l + k * 128;
        *(ull_t*)&Abuf[j >> 7][256 + 4 * (j & 127)] = gv[k];
      }
    } else {
      #pragma unroll
      for (int kc = 0; kc < 8; kc += 2) {
        ga0 = MFMA(LDA(kc), wfrag[kc], ga0);
        ga1 = MFMA(LDA(kc + 1), wfrag[kc + 1], ga1);
      }
      #pragma unroll
      for (int kc = 24; kc < 40; kc += 2) {
        ga0 = MFMA(LDA(kc), wfrag[kc], ga0);
        ga1 = MFMA(LDA(kc + 1), wfrag[kc + 1], ga1);
      }
    }
    __syncthreads();   // S1: ghost staged; safe to read [256..768)

    // x_{t+1} prefetch issue (drains at the 3t+1 barrier, covered by MFMAs)
    {
      const int tn = (t + 1 < NT) ? t + 1 : t;
      #pragma unroll
      for (int k = 0; k < 4; ++k) {
        int i = tid + k * 256;
        xv[k] = *(const float4*)&x[((size_t)(b0 + (i >> 6)) * NT + tn) * NF + (i & 63) * 4];
      }
    }

    // ---- B: phase-1 completion (wv0/1: ghost frags 8..23 + activation);
    //      wave 2: its 24 x+ghost cand frags. ----
    if (wv < 2) {
      #pragma unroll
      for (int kc = 8; kc < 24; kc += 2) {
        ga0 = MFMA(LDA(kc), wfrag[kc], ga0);
        ga1 = MFMA(LDA(kc + 1), wfrag[kc + 1], ga1);
      }
      const int n = ncol0 + ln;
      if (wv == 0) {      // r-gate -> rstate = r * h_old[newh part] (cross-WG)
        #pragma unroll
        for (int r = 0; r < 4; ++r) {
          int row = lq * 4 + r;
          float s = sigmoidf_(ga0[r] + ga1[r] + biasv);
          float hold = bf2f(Abuf[row][768 + n]);
          unsigned hv = (unsigned)f2bf(s * hold);
          unsigned pv = (unsigned)__shfl_xor((int)hv, 1);
          if (!(ln & 1))
            AT_STORE(&rs_u[(size_t)(b0 + row) * 256 + (n >> 1)], hv | (pv << 16));
        }
      } else {            // u-gate -> LDS only (consumed by this WG's cand wave)
        #pragma unroll
        for (int r = 0; r < 4; ++r) {
          int row = lq * 4 + r;
          float s = sigmoidf_(ga0[r] + ga1[r] + biasv);
          ((float*)&Abuf[row][1792])[ln] = s;
        }
      }
    } else if (wv == 2) {
      #pragma unroll
      for (int kc = 0; kc < 24; kc += 2) {
        ca0 = MFMA(LDA(kc), wfrag[kc], ca0);
        ca1 = MFMA(LDA(kc + 1), wfrag[kc + 1], ca1);
      }
    }
    post_flag(flags, memb, 3u * (unsigned)t + 1u);

    // ---- C: rstate exchange. Waves 0/1 poll + stage (16 ull each);
    //      waves 2/3 skip the poll (S2 gates their reads). Wave 2 reads u. ----
    float uval[4];
    if (wv == 2) {        // u from LDS (written by wave 1 before the barrier)
      #pragma unroll
      for (int r = 0; r < 4; ++r)
        uval[r] = ((const float*)&Abuf[lq * 4 + r][1792])[ln];
    }
    if (wv < 2) {
      wait_flags(flags, 3u * (unsigned)t + 1u);
      ull_t rv[16];
      #pragma unroll
      for (int k = 0; k < 16; ++k) {
        int j = tid + k * 128;               // tid<128 here; covers 0..2047
        rv[k] = AT_LOAD(&rs64[(size_t)(b0 + (j >> 7)) * 128 + (j & 127)]);
      }
      #pragma unroll
      for (int k = 0; k < 16; ++k) {
        int j = tid + k * 128;
        *(ull_t*)&Abuf[j >> 7][1280 + 4 * (j & 127)] = rv[k];
      }
    }
    __syncthreads();   // S2: rstate staged

    // ---- D: phase-2 late (wv2): rstate frags 24..39, hnew, state stores ----
    float hn[4];
    if (wv == 2) {
      #pragma unroll
      for (int kc = 24; kc < 40; kc += 2) {
        ca0 = MFMA(LDR(kc), wfrag[kc], ca0);
        ca1 = MFMA(LDR(kc + 1), wfrag[kc + 1], ca1);
      }
      const int n = ncol0 + ln;
      #pragma unroll
      for (int r = 0; r < 4; ++r) {
        int row = lq * 4 + r;
        float cv = tanhf_(ca0[r] + ca1[r] + biasv);
        float u = uval[r];
        float hnew = u * hreg[r] + (1.f - u) * cv;
        hreg[r] = hnew; hn[r] = hnew;
        unsigned hv = (unsigned)f2bf(hnew);
        unsigned pv = (unsigned)__shfl_xor((int)hv, 1);
        if (!(ln & 1))
          AT_STORE(&hdst[(size_t)(b0 + row) * 512 + 256 + (n >> 1)], hv | (pv << 16));
      }
    }
    post_flag(flags, memb, 3u * (unsigned)t + 2u);
    if (wv == 2) {        // deferred out stores: drain inside the E window
      const int n = ncol0 + ln;
      #pragma unroll
      for (int r = 0; r < 4; ++r) {
        int b = b0 + lq * 4 + r;
        out[((size_t)b * NT + t) * NH + 512 + n] = hn[r];
        if (t == NT - 1) out[(size_t)NB * NT * NH + (size_t)b * NH + 512 + n] = hn[r];
      }
    }

    // ---- E: x_{t+1} conversion (no wait needed: x readers all pre-3t+1);
    //      then waves 0/1 poll + stage newh (16 ull each); 2/3 -> S3. ----
    #pragma unroll
    for (int k = 0; k < 4; ++k) {
      int i = tid + k * 256;
      int row = i >> 6, c4 = (i & 63) * 4;
      *(ushort4*)&Abuf[row][c4] =
          make_ushort4(f2bf(xv[k].x), f2bf(xv[k].y), f2bf(xv[k].z), f2bf(xv[k].w));
    }
    if (wv < 2) {
      wait_flags(flags, 3u * (unsigned)t + 2u);
      ull_t nv[16];
      #pragma unroll
      for (int k = 0; k < 16; ++k) {
        int j = tid + k * 128;               // tid<128; covers 0..2047
        nv[k] = AT_LOAD(&hdst64[(size_t)(b0 + (j >> 7)) * 256 + 128 + (j & 127)]);
      }
      #pragma unroll
      for (int k = 0; k < 16; ++k) {
        int j = tid + k * 128;
        *(ull_t*)&Abuf[j >> 7][768 + 4 * (j & 127)] = nv[k];
      }
    }
    __syncthreads();   // S3: newh_t + x_{t+1} staged

    // ---- F: phase 3 (wv3): ghost GEMM, state stores; post; deferred out ----
    float gvv[4];
    if (wv == 3) {
      f32x4 acc = {0.f, 0.f, 0.f, 0.f};
      #pragma unroll
      for (int kc = 0; kc < 16; ++kc)
        acc = MFMA((*(const short8*)&Abuf[ln][768 + kc * 32 + lq * 8]), wfrag[kc], acc);
      const int n = ncol0 + ln;
      #pragma unroll
      for (int r = 0; r < 4; ++r) {
        int row = lq * 4 + r;
        float gv = tanhf_(acc[r] + biasv);
        gvv[r] = gv;
        unsigned hv = (unsigned)f2bf(gv);
        unsigned pv = (unsigned)__shfl_xor((int)hv, 1);
        if (!(ln & 1))
          AT_STORE(&hdst[(size_t)(b0 + row) * 512 + (n >> 1)], hv | (pv << 16));
      }
    }
    post_flag(flags, memb, 3u * (unsigned)t + 3u);
    if (wv == 3) {        // deferred out stores: drain at next loop-top window
      const int n = ncol0 + ln;
      #pragma unroll
      for (int r = 0; r < 4; ++r) {
        int b = b0 + lq * 4 + r;
        out[((size_t)b * NT + t) * NH + n] = gvv[r];
        if (t == NT - 1) out[(size_t)NB * NT * NH + (size_t)b * NH + n] = gvv[r];
      }
    }
    // no trailing wait: loop-top (waves 2/3) waits 3(t+1); waves 0/1 are
    // gated transitively by S1.
  }
  #undef LDA
  #undef LDR
  #undef MFMA
}

__global__ void init_kernel(const float* __restrict__ hidden,
                            unsigned int* __restrict__ hbuf_u,
                            unsigned int* __restrict__ counters) {
  int i = blockIdx.x * blockDim.x + threadIdx.x;
  if (i < NB * 512) {  // pack h0 into bf16 pairs; hbuf[0] = h0
    unsigned lo = (unsigned)f2bf(hidden[2 * i]);
    unsigned hi = (unsigned)f2bf(hidden[2 * i + 1]);
    hbuf_u[i] = lo | (hi << 16);
  }
  if (i < 512) counters[i] = 0;  // 8 groups x 64-uint flag blocks
}

extern "C" void kernel_launch(void* const* d_in, const int* in_sizes, int n_in,
                              void* d_out, int out_size, void* d_ws, size_t ws_size,
                              hipStream_t stream) {
  (void)in_sizes; (void)n_in; (void)out_size; (void)ws_size;
  const float* x      = (const float*)d_in[0];
  const float* hidden = (const float*)d_in[1];
  const float* Wg     = (const float*)d_in[2];
  const float* Wc     = (const float*)d_in[3];
  const float* Wgh    = (const float*)d_in[4];
  const float* bg     = (const float*)d_in[5];
  const float* bc     = (const float*)d_in[6];
  const float* bgh    = (const float*)d_in[7];
  float* out = (float*)d_out;

  char* ws = (char*)d_ws;
  unsigned int* hbuf_u   = (unsigned int*)(ws);         // 2 * 128*512 uints = 512 KB
  unsigned int* rs_u     = (unsigned int*)(ws + 524288);// 128*256 uints = 128 KB
  unsigned int* counters = (unsigned int*)(ws + 655360);// 512 uints = 2 KB

  init_kernel<<<dim3(256), dim3(256), 0, stream>>>(hidden, hbuf_u, counters);
  ghost_gru_persistent<<<dim3(256), dim3(256), 0, stream>>>(
      x, hidden, Wg, Wc, Wgh, bg, bc, bgh, out, hbuf_u, rs_u, counters);
}